// Round 12
// baseline (106.010 us; speedup 1.0000x reference)
//
#include <hip/hip_runtime.h>

// Problem constants (match reference): B=64, L=2048, H=256, K=32
#define LL 2048
#define BB 64
#define HH 256
#define KK 32

#define NB  1024   // 4 blocks/CU exactly (LDS ~33.4 KB/block)
#define WPB 4      // waves per block

typedef __attribute__((ext_vector_type(8))) short  short8;   // 8 bf16 (4 VGPRs)
typedef __attribute__((ext_vector_type(4))) float  f32x4;

__device__ __forceinline__ float softplus_f(float x) {
    return x > 20.f ? x : __logf(1.f + __expf(x));
}
// round-to-nearest-even fp32 -> bf16
__device__ __forceinline__ unsigned f2bf(float x) {
    unsigned u = __builtin_bit_cast(unsigned, x);
    return (u + 0x7FFFu + ((u >> 16) & 1u)) >> 16;
}
__device__ __forceinline__ float bfhi(unsigned u) {   // high bf16 -> f32
    return __builtin_bit_cast(float, u & 0xFFFF0000u);
}
__device__ __forceinline__ float bflo(unsigned u) {   // low bf16 -> f32
    return __builtin_bit_cast(float, u << 16);
}

struct RowT { float4 h, c, t, o, d; };

__device__ __forceinline__ RowT load_row(
    const float* __restrict__ hidden, const float* __restrict__ cell,
    const float* __restrict__ ctarg,  const float* __restrict__ outp,
    const float* __restrict__ decay,  int r, int lane)
{
    const int base = r * HH + lane * 4;
    RowT x;
    x.h = *(const float4*)(hidden + base);
    x.c = *(const float4*)(cell   + base);
    x.t = *(const float4*)(ctarg  + base);
    x.o = *(const float4*)(outp   + base);
    x.d = *(const float4*)(decay  + base);
    return x;
}

// Compute v-row J, write to swizzled LDS A-tile; return this lane's term-1
// partial dot(h-slice, W[:, ej]-slice). No captured-local writes (spill-safe).
template<int J>
__device__ __forceinline__ float proc_row(char* Aw, const char* WTs,
                                          const RowT& R, float stv, int ej, int lane)
{
    float4 v;
    float cs, e2;
    cs = R.t.x + (R.c.x - R.t.x) * __expf(-R.d.x * stv); e2 = __expf(2.f * cs); v.x = R.o.x * ((e2 - 1.f) / (e2 + 1.f));
    cs = R.t.y + (R.c.y - R.t.y) * __expf(-R.d.y * stv); e2 = __expf(2.f * cs); v.y = R.o.y * ((e2 - 1.f) / (e2 + 1.f));
    cs = R.t.z + (R.c.z - R.t.z) * __expf(-R.d.z * stv); e2 = __expf(2.f * cs); v.z = R.o.z * ((e2 - 1.f) / (e2 + 1.f));
    cs = R.t.w + (R.c.w - R.t.w) * __expf(-R.d.w * stv); e2 = __expf(2.f * cs); v.w = R.o.w * ((e2 - 1.f) / (e2 + 1.f));
    *(uint2*)(Aw + ((J * 512 + lane * 8) ^ ((J & 7) << 4))) =
        make_uint2(f2bf(v.x) | (f2bf(v.y) << 16), f2bf(v.z) | (f2bf(v.w) << 16));
    const uint2 wc = *(const uint2*)(WTs + ((ej * 512 + lane * 8) ^ ((ej & 7) << 4)));
    return R.h.x * bflo(wc.x) + R.h.y * bfhi(wc.x)
         + R.h.z * bflo(wc.y) + R.h.w * bfhi(wc.y);
}

// 8 flat rows per wave-tile. Per-wave LDS A-tile = 8 v-rows (4 KB, swizzled);
// hidden never touches LDS (term 1 = per-lane partials + batched 10-shuffle
// reduce-scatter on NAMED scalars). 3-deep load rotation. MFMA C rows 0-7 =
// v-dots (term 2); rows 8-15 duplicates, masked by g<2 guard.
__global__ __launch_bounds__(256, 3) void nhll_main(
    const int*   __restrict__ events,   // [B, L]
    const int*   __restrict__ lens,     // [B]
    const float* __restrict__ ttime,    // [B]
    const float* __restrict__ hidden,   // [L, B, H]
    const float* __restrict__ cell,     // [L, B, H]
    const float* __restrict__ ctarg,    // [L, B, H]
    const float* __restrict__ outp,     // [L, B, H]
    const float* __restrict__ decay,    // [L, B, H]
    const float* __restrict__ simt,     // [L, B]
    const float* __restrict__ W,        // [H, K]
    const float* __restrict__ bias,     // [K]
    float*       __restrict__ partial)  // [NB]
{
    __shared__ __align__(16) char  WTs[KK * HH * 2];       // 16 KB W^T bf16, swizzled
    __shared__ __align__(16) char  Als[WPB][8 * HH * 2];   // 4 KB per wave (v-rows)
    __shared__ int   pfx[BB + 1];
    __shared__ float coef_s[BB];
    __shared__ float bias_s[KK];
    __shared__ float wacc[WPB];

    const int tid  = threadIdx.x;
    const int lane = tid & 63;
    const int q    = tid >> 6;
    const int g    = lane >> 4;     // h-octet within K-chunk
    const int m    = lane & 15;     // C-col index

    // ---- one-time: W^T bf16 into LDS (row k, position h=tid, swizzled) ----
    {
        const float* wrow = &W[tid * KK];
#pragma unroll
        for (int k = 0; k < KK; ++k) {
            const int byte = (k * 512 + tid * 2) ^ ((k & 7) << 4);
            *(unsigned short*)(WTs + byte) = (unsigned short)f2bf(wrow[k]);
        }
    }
    if (tid < KK) bias_s[tid] = bias[tid];
    if (tid < BB) {                 // wave 0: scan lens -> prefix sums
        const int ln = lens[tid];
        coef_s[tid] = ttime[tid] / (float)ln;
        int s = ln;
#pragma unroll
        for (int mm = 1; mm < 64; mm <<= 1) {
            const int t = __shfl_up(s, mm, 64);
            if (lane >= mm) s += t;
        }
        pfx[tid + 1] = s;
        if (tid == 0) pfx[0] = 0;
    }
    __syncthreads();

    const float b_lo = bias[m];
    const float b_hi = bias[16 + m];
    const int   T      = pfx[BB];
    const int   ntiles = (T + 7) >> 3;
    // j held by this lane after the reduce-scatter (bits 5,4,3 of lane)
    const int   jj = 4 * ((lane >> 5) & 1) + 2 * ((lane >> 4) & 1) + ((lane >> 3) & 1);
    char* Aw = Als[q];
    float acc = 0.f;

    for (int tile = blockIdx.x * WPB + q; tile < ntiles; tile += NB * WPB) {
        // ---- parallel metadata: lane j (j = lane&7) owns flat row tile*8+j ----
        int i = tile * 8 + (lane & 7);
        const int valid = (i < T) ? 1 : 0;
        if (!valid) i = T - 1;                    // clamp; masked below
        int lo = 0, hi = BB;
#pragma unroll
        for (int s = 0; s < 6; ++s) {
            const int mid = (lo + hi) >> 1;
            if (pfx[mid] <= i) lo = mid; else hi = mid;
        }
        const int   b    = lo;
        const int   l    = i - pfx[b];
        const int   r    = l * BB + b;
        const float st   = simt[r];
        const float coef = valid ? coef_s[b] : 0.f;
        const int   e    = events[b * LL + l + 1];   // l+1 <= len <= 2046

        const int   r0 = __shfl(r, 0, 64), r1 = __shfl(r, 1, 64),
                    r2 = __shfl(r, 2, 64), r3 = __shfl(r, 3, 64),
                    r4 = __shfl(r, 4, 64), r5 = __shfl(r, 5, 64),
                    r6 = __shfl(r, 6, 64), r7 = __shfl(r, 7, 64);
        const float s0 = __shfl(st, 0, 64), s1 = __shfl(st, 1, 64),
                    s2 = __shfl(st, 2, 64), s3 = __shfl(st, 3, 64),
                    s4 = __shfl(st, 4, 64), s5 = __shfl(st, 5, 64),
                    s6 = __shfl(st, 6, 64), s7 = __shfl(st, 7, 64);
        const int   e0 = __shfl(e, 0, 64), e1 = __shfl(e, 1, 64),
                    e2_ = __shfl(e, 2, 64), e3 = __shfl(e, 3, 64),
                    e4 = __shfl(e, 4, 64), e5 = __shfl(e, 5, 64),
                    e6 = __shfl(e, 6, 64), e7 = __shfl(e, 7, 64);

        // ---- staging: 3-deep rotation, named buffers, named su scalars ----
        RowT b0 = load_row(hidden, cell, ctarg, outp, decay, r0, lane);
        RowT b1 = load_row(hidden, cell, ctarg, outp, decay, r1, lane);
        RowT b2 = load_row(hidden, cell, ctarg, outp, decay, r2, lane);
        float u0 = proc_row<0>(Aw, WTs, b0, s0, e0, lane);
        b0 = load_row(hidden, cell, ctarg, outp, decay, r3, lane);
        float u1 = proc_row<1>(Aw, WTs, b1, s1, e1, lane);
        b1 = load_row(hidden, cell, ctarg, outp, decay, r4, lane);
        float u2 = proc_row<2>(Aw, WTs, b2, s2, e2_, lane);
        b2 = load_row(hidden, cell, ctarg, outp, decay, r5, lane);
        float u3 = proc_row<3>(Aw, WTs, b0, s3, e3, lane);
        b0 = load_row(hidden, cell, ctarg, outp, decay, r6, lane);
        float u4 = proc_row<4>(Aw, WTs, b1, s4, e4, lane);
        b1 = load_row(hidden, cell, ctarg, outp, decay, r7, lane);
        float u5 = proc_row<5>(Aw, WTs, b2, s5, e5, lane);
        float u6 = proc_row<6>(Aw, WTs, b0, s6, e6, lane);
        float u7 = proc_row<7>(Aw, WTs, b1, s7, e7, lane);

        // ---- term 1 batched reduce-scatter on named scalars ----
        {   // mask 32, pairs (u0,u4)(u1,u5)(u2,u6)(u3,u7)
            const bool h_ = (lane & 32) != 0;
            const float k0 = h_ ? u4 : u0, t0 = h_ ? u0 : u4;
            const float k1 = h_ ? u5 : u1, t1 = h_ ? u1 : u5;
            const float k2 = h_ ? u6 : u2, t2 = h_ ? u2 : u6;
            const float k3 = h_ ? u7 : u3, t3 = h_ ? u3 : u7;
            u0 = k0 + __shfl_xor(t0, 32, 64);
            u1 = k1 + __shfl_xor(t1, 32, 64);
            u2 = k2 + __shfl_xor(t2, 32, 64);
            u3 = k3 + __shfl_xor(t3, 32, 64);
        }
        {   // mask 16, pairs (u0,u2)(u1,u3)
            const bool h_ = (lane & 16) != 0;
            const float k0 = h_ ? u2 : u0, t0 = h_ ? u0 : u2;
            const float k1 = h_ ? u3 : u1, t1 = h_ ? u1 : u3;
            u0 = k0 + __shfl_xor(t0, 16, 64);
            u1 = k1 + __shfl_xor(t1, 16, 64);
        }
        {   // mask 8, pair (u0,u1)
            const bool h_ = (lane & 8) != 0;
            const float k0 = h_ ? u1 : u0, t0 = h_ ? u0 : u1;
            u0 = k0 + __shfl_xor(t0, 8, 64);
        }
        u0 += __shfl_xor(u0, 4, 64);
        u0 += __shfl_xor(u0, 2, 64);
        u0 += __shfl_xor(u0, 1, 64);
        // lane group holds S_{jj}; lanes 8*jj commit row jj
        {
            const int ejj = __shfl(e, jj, 64);
            const int vjj = __shfl(valid, jj, 64);
            if ((lane & 7) == 0 && vjj)
                acc -= __logf(softplus_f(u0 + bias_s[ejj]));
        }

        // ---- MFMA: C rows 0-7 useful (lanes m>=8 re-read rows m-8) ----
        f32x4 C0 = {0.f,0.f,0.f,0.f}, C1 = {0.f,0.f,0.f,0.f};
        const int abase = (m & 7) * 512 + 16 * g;    // A-row (dup for m>=8)
        const int wbase = m * 512 + 16 * g;
        const int swza  = (m & 7) << 4;
#pragma unroll
        for (int c = 0; c < 8; ++c) {
            const short8 a  = *(const short8*)(Aw  + ((abase + 64 * c) ^ swza));
            const short8 w0 = *(const short8*)(WTs + ((wbase + 64 * c) ^ swza));
            const short8 w1 = *(const short8*)(WTs + ((wbase + 8192 + 64 * c) ^ swza));
            C0 = __builtin_amdgcn_mfma_f32_16x16x32_bf16(a, w0, C0, 0, 0, 0);
            C1 = __builtin_amdgcn_mfma_f32_16x16x32_bf16(a, w1, C1, 0, 0, 0);
        }

        // ---- term 2: C rows 0-7 (g<2), row = 4g+reg, col = m ----
        float sp[4];
#pragma unroll
        for (int reg = 0; reg < 4; ++reg)
            sp[reg] = softplus_f(C0[reg] + b_lo) + softplus_f(C1[reg] + b_hi);
#pragma unroll
        for (int mk = 1; mk <= 8; mk <<= 1) {
#pragma unroll
            for (int reg = 0; reg < 4; ++reg) sp[reg] += __shfl_xor(sp[reg], mk, 64);
        }
        float t2 = 0.f;
#pragma unroll
        for (int reg = 0; reg < 4; ++reg) {
            const float cf = __shfl(coef, 4 * g + reg, 64);  // coef of flat row 4g+reg
            t2 += cf * sp[reg];
        }
        if (m == 0 && g < 2) acc += t2;
    }

    // wave reduce + block reduce
#pragma unroll
    for (int mk = 1; mk < 64; mk <<= 1) acc += __shfl_xor(acc, mk, 64);
    if (lane == 0) wacc[q] = acc;
    __syncthreads();
    if (tid == 0) partial[blockIdx.x] = wacc[0] + wacc[1] + wacc[2] + wacc[3];
}

// Output: single float32 scalar.
__global__ __launch_bounds__(256) void nhll_finalize(
    const float* __restrict__ partial, float* __restrict__ out)
{
    __shared__ float red[4];
    float s = 0.f;
    for (int i = threadIdx.x; i < NB; i += 256) s += partial[i];
    for (int mk = 1; mk < 64; mk <<= 1) s += __shfl_xor(s, mk, 64);
    if ((threadIdx.x & 63) == 0) red[threadIdx.x >> 6] = s;
    __syncthreads();
    if (threadIdx.x == 0)
        out[0] = red[0] + red[1] + red[2] + red[3];
}

extern "C" void kernel_launch(void* const* d_in, const int* in_sizes, int n_in,
                              void* d_out, int out_size, void* d_ws, size_t ws_size,
                              hipStream_t stream) {
    const int*   events = (const int*)  d_in[0];   // event_seqs  [B,L] int32
    const int*   lens   = (const int*)  d_in[1];   // seqs_length [B]   int32
    const float* ttime  = (const float*)d_in[2];   // total_time  [B]
    const float* hidden = (const float*)d_in[3];   // [L,B,H]
    const float* cell   = (const float*)d_in[4];   // [L,B,H]
    const float* ctarg  = (const float*)d_in[5];   // [L,B,H]
    const float* outp   = (const float*)d_in[6];   // [L,B,H]
    const float* decay  = (const float*)d_in[7];   // [L,B,H]
    const float* simt   = (const float*)d_in[8];   // [L,B]
    const float* W      = (const float*)d_in[9];   // [H,K]
    const float* bias   = (const float*)d_in[10];  // [K]

    float* part = (float*)d_ws;                    // NB floats
    float* out  = (float*)d_out;

    nhll_main<<<NB, 256, 0, stream>>>(events, lens, ttime, hidden, cell, ctarg,
                                      outp, decay, simt, W, bias, part);
    nhll_finalize<<<1, 256, 0, stream>>>(part, out);
}

// Round 13
// 76.338 us; speedup vs baseline: 1.3887x; 1.3887x over previous
//
#include <hip/hip_runtime.h>

// Problem constants (match reference): B=64, L=2048, H=256, K=32
#define LL 2048
#define BB 64
#define HH 256
#define KK 32

#define NB  1024   // 4 blocks/CU exactly (LDS ~33.4 KB/block)
#define WPB 4      // waves per block

typedef __attribute__((ext_vector_type(8))) short  short8;   // 8 bf16 (4 VGPRs)
typedef __attribute__((ext_vector_type(4))) float  f32x4;

__device__ __forceinline__ float softplus_f(float x) {
    return x > 20.f ? x : __logf(1.f + __expf(x));
}
// round-to-nearest-even fp32 -> bf16
__device__ __forceinline__ unsigned f2bf(float x) {
    unsigned u = __builtin_bit_cast(unsigned, x);
    return (u + 0x7FFFu + ((u >> 16) & 1u)) >> 16;
}

struct Row4 { float4 c, t, o, d; };   // 16 VGPR (h loaded separately in pass B)

__device__ __forceinline__ Row4 load_row4(
    const float* __restrict__ cell, const float* __restrict__ ctarg,
    const float* __restrict__ outp, const float* __restrict__ decay,
    int r, int lane)
{
    const int base = r * HH + lane * 4;
    Row4 x;
    x.c = *(const float4*)(cell  + base);
    x.t = *(const float4*)(ctarg + base);
    x.o = *(const float4*)(outp  + base);
    x.d = *(const float4*)(decay + base);
    return x;
}

// v-row J: compute o*tanh(c_sim), write bf16x4 to swizzled A-tile row J.
template<int J>
__device__ __forceinline__ void st_v(char* Aw, const Row4& R, float stv, int lane)
{
    float4 v;
    float cs, e2;
    cs = R.t.x + (R.c.x - R.t.x) * __expf(-R.d.x * stv); e2 = __expf(2.f * cs); v.x = R.o.x * ((e2 - 1.f) / (e2 + 1.f));
    cs = R.t.y + (R.c.y - R.t.y) * __expf(-R.d.y * stv); e2 = __expf(2.f * cs); v.y = R.o.y * ((e2 - 1.f) / (e2 + 1.f));
    cs = R.t.z + (R.c.z - R.t.z) * __expf(-R.d.z * stv); e2 = __expf(2.f * cs); v.z = R.o.z * ((e2 - 1.f) / (e2 + 1.f));
    cs = R.t.w + (R.c.w - R.t.w) * __expf(-R.d.w * stv); e2 = __expf(2.f * cs); v.w = R.o.w * ((e2 - 1.f) / (e2 + 1.f));
    *(uint2*)(Aw + ((J * 512 + lane * 8) ^ ((J & 7) << 4))) =
        make_uint2(f2bf(v.x) | (f2bf(v.y) << 16), f2bf(v.z) | (f2bf(v.w) << 16));
}

// h-row J: write bf16x4 to the SAME swizzled A-tile row J (pass B overwrite;
// in-wave DS ops execute in order, so pass-A reads have already returned).
template<int J>
__device__ __forceinline__ void st_h(char* Aw, const float4& h, int lane)
{
    *(uint2*)(Aw + ((J * 512 + lane * 8) ^ ((J & 7) << 4))) =
        make_uint2(f2bf(h.x) | (f2bf(h.y) << 16), f2bf(h.z) | (f2bf(h.w) << 16));
}

// 8 flat rows per wave-tile; 4 KB/wave A-tile used TWICE per tile:
// pass A = v-rows -> MFMA -> term 2; pass B = h-rows -> MFMA -> term 1.
// 3-deep load rotation in both passes; pass-B loads issued under MFMA-A.
__global__ __launch_bounds__(256, 3) void nhll_main(
    const int*   __restrict__ events,   // [B, L]
    const int*   __restrict__ lens,     // [B]
    const float* __restrict__ ttime,    // [B]
    const float* __restrict__ hidden,   // [L, B, H]
    const float* __restrict__ cell,     // [L, B, H]
    const float* __restrict__ ctarg,    // [L, B, H]
    const float* __restrict__ outp,     // [L, B, H]
    const float* __restrict__ decay,    // [L, B, H]
    const float* __restrict__ simt,     // [L, B]
    const float* __restrict__ W,        // [H, K]
    const float* __restrict__ bias,     // [K]
    float*       __restrict__ partial)  // [NB]
{
    __shared__ __align__(16) char  WTs[KK * HH * 2];       // 16 KB W^T bf16, swizzled
    __shared__ __align__(16) char  Als[WPB][8 * HH * 2];   // 4 KB per wave
    __shared__ int   pfx[BB + 1];
    __shared__ float coef_s[BB];
    __shared__ float bias_s[KK];
    __shared__ float wacc[WPB];

    const int tid  = threadIdx.x;
    const int lane = tid & 63;
    const int q    = tid >> 6;
    const int g    = lane >> 4;     // h-octet within K-chunk
    const int m    = lane & 15;     // C-col index

    // ---- one-time: W^T bf16 into LDS (row k, position h=tid, swizzled) ----
    {
        const float* wrow = &W[tid * KK];
#pragma unroll
        for (int k = 0; k < KK; ++k) {
            const int byte = (k * 512 + tid * 2) ^ ((k & 7) << 4);
            *(unsigned short*)(WTs + byte) = (unsigned short)f2bf(wrow[k]);
        }
    }
    if (tid < KK) bias_s[tid] = bias[tid];
    if (tid < BB) {                 // wave 0: scan lens -> prefix sums
        const int ln = lens[tid];
        coef_s[tid] = ttime[tid] / (float)ln;
        int s = ln;
#pragma unroll
        for (int mm = 1; mm < 64; mm <<= 1) {
            const int t = __shfl_up(s, mm, 64);
            if (lane >= mm) s += t;
        }
        pfx[tid + 1] = s;
        if (tid == 0) pfx[0] = 0;
    }
    __syncthreads();

    const float b_lo = bias[m];
    const float b_hi = bias[16 + m];
    const int   T      = pfx[BB];
    const int   ntiles = (T + 7) >> 3;
    char* Aw = Als[q];
    float acc = 0.f;

    for (int tile = blockIdx.x * WPB + q; tile < ntiles; tile += NB * WPB) {
        // ---- parallel metadata: lane j (j = lane&7) owns flat row tile*8+j ----
        int i = tile * 8 + (lane & 7);
        const int valid = (i < T) ? 1 : 0;
        if (!valid) i = T - 1;                    // clamp; masked below
        int lo = 0, hi = BB;
#pragma unroll
        for (int s = 0; s < 6; ++s) {
            const int mid = (lo + hi) >> 1;
            if (pfx[mid] <= i) lo = mid; else hi = mid;
        }
        const int   b    = lo;
        const int   l    = i - pfx[b];
        const int   r    = l * BB + b;
        const float st   = simt[r];
        const float coef = valid ? coef_s[b] : 0.f;
        const int   e    = events[b * LL + l + 1];   // l+1 <= len <= 2046

        const int   r0 = __shfl(r, 0, 64), r1 = __shfl(r, 1, 64),
                    r2 = __shfl(r, 2, 64), r3 = __shfl(r, 3, 64),
                    r4 = __shfl(r, 4, 64), r5 = __shfl(r, 5, 64),
                    r6 = __shfl(r, 6, 64), r7 = __shfl(r, 7, 64);
        const float s0 = __shfl(st, 0, 64), s1 = __shfl(st, 1, 64),
                    s2 = __shfl(st, 2, 64), s3 = __shfl(st, 3, 64),
                    s4 = __shfl(st, 4, 64), s5 = __shfl(st, 5, 64),
                    s6 = __shfl(st, 6, 64), s7 = __shfl(st, 7, 64);

        // ---- pass A staging: 3-deep rotation over {c,t,o,d} ----
        Row4 b0 = load_row4(cell, ctarg, outp, decay, r0, lane);
        Row4 b1 = load_row4(cell, ctarg, outp, decay, r1, lane);
        Row4 b2 = load_row4(cell, ctarg, outp, decay, r2, lane);
        st_v<0>(Aw, b0, s0, lane); b0 = load_row4(cell, ctarg, outp, decay, r3, lane);
        st_v<1>(Aw, b1, s1, lane); b1 = load_row4(cell, ctarg, outp, decay, r4, lane);
        st_v<2>(Aw, b2, s2, lane); b2 = load_row4(cell, ctarg, outp, decay, r5, lane);
        st_v<3>(Aw, b0, s3, lane); b0 = load_row4(cell, ctarg, outp, decay, r6, lane);
        st_v<4>(Aw, b1, s4, lane); b1 = load_row4(cell, ctarg, outp, decay, r7, lane);
        st_v<5>(Aw, b2, s5, lane);
        st_v<6>(Aw, b0, s6, lane);
        st_v<7>(Aw, b1, s7, lane);

        // issue first pass-B h loads; they land under MFMA-A + term-2
        float4 h0 = *(const float4*)(hidden + r0 * HH + lane * 4);
        float4 h1 = *(const float4*)(hidden + r1 * HH + lane * 4);
        float4 h2 = *(const float4*)(hidden + r2 * HH + lane * 4);

        const int abase = (m & 7) * 512 + 16 * g;    // A-row (rows 8-15 dup)
        const int wbase = m * 512 + 16 * g;
        const int swza  = (m & 7) << 4;

        // ---- MFMA pass A: v-dots ----
        f32x4 C0 = {0.f,0.f,0.f,0.f}, C1 = {0.f,0.f,0.f,0.f};
#pragma unroll
        for (int c = 0; c < 8; ++c) {
            const short8 a  = *(const short8*)(Aw  + ((abase + 64 * c) ^ swza));
            const short8 w0 = *(const short8*)(WTs + ((wbase + 64 * c) ^ swza));
            const short8 w1 = *(const short8*)(WTs + ((wbase + 8192 + 64 * c) ^ swza));
            C0 = __builtin_amdgcn_mfma_f32_16x16x32_bf16(a, w0, C0, 0, 0, 0);
            C1 = __builtin_amdgcn_mfma_f32_16x16x32_bf16(a, w1, C1, 0, 0, 0);
        }

        // ---- term 2: C rows 0-7 (g<2), row = 4g+reg, col = m ----
        float sp[4];
#pragma unroll
        for (int reg = 0; reg < 4; ++reg)
            sp[reg] = softplus_f(C0[reg] + b_lo) + softplus_f(C1[reg] + b_hi);
#pragma unroll
        for (int mk = 1; mk <= 8; mk <<= 1) {
#pragma unroll
            for (int reg = 0; reg < 4; ++reg) sp[reg] += __shfl_xor(sp[reg], mk, 64);
        }
        float t2 = 0.f;
#pragma unroll
        for (int reg = 0; reg < 4; ++reg) {
            const float cf = __shfl(coef, 4 * g + reg, 64);  // coef of flat row 4g+reg
            t2 += cf * sp[reg];
        }
        if (m == 0 && g < 2) acc += t2;

        // ---- pass B staging: h-rows overwrite the A-tile (3-deep rotation) ----
        st_h<0>(Aw, h0, lane); h0 = *(const float4*)(hidden + r3 * HH + lane * 4);
        st_h<1>(Aw, h1, lane); h1 = *(const float4*)(hidden + r4 * HH + lane * 4);
        st_h<2>(Aw, h2, lane); h2 = *(const float4*)(hidden + r5 * HH + lane * 4);
        st_h<3>(Aw, h0, lane); h0 = *(const float4*)(hidden + r6 * HH + lane * 4);
        st_h<4>(Aw, h1, lane); h1 = *(const float4*)(hidden + r7 * HH + lane * 4);
        st_h<5>(Aw, h2, lane);
        st_h<6>(Aw, h0, lane);
        st_h<7>(Aw, h1, lane);

        // ---- MFMA pass B: h-dots ----
        f32x4 D0 = {0.f,0.f,0.f,0.f}, D1 = {0.f,0.f,0.f,0.f};
#pragma unroll
        for (int c = 0; c < 8; ++c) {
            const short8 a  = *(const short8*)(Aw  + ((abase + 64 * c) ^ swza));
            const short8 w0 = *(const short8*)(WTs + ((wbase + 64 * c) ^ swza));
            const short8 w1 = *(const short8*)(WTs + ((wbase + 8192 + 64 * c) ^ swza));
            D0 = __builtin_amdgcn_mfma_f32_16x16x32_bf16(a, w0, D0, 0, 0, 0);
            D1 = __builtin_amdgcn_mfma_f32_16x16x32_bf16(a, w1, D1, 0, 0, 0);
        }

        // ---- term 1: C rows 0-7 gathered at column e_rr ----
        float kv = 0.f, kb = 0.f;
#pragma unroll
        for (int rr = 0; rr < 8; ++rr) {
            const int   er   = __shfl(e, rr, 64);            // e of flat row rr
            const float cand = (er < 16) ? D0[rr & 3] : D1[rr & 3];
            const float val  = __shfl(cand, ((rr >> 2) << 4) + (er & 15), 64);
            const float be   = bias_s[er];                   // uniform broadcast
            if (lane == rr) { kv = val; kb = be; }
        }
        if (lane < 8 && valid)
            acc -= __logf(softplus_f(kv + kb));
    }

    // wave reduce + block reduce
#pragma unroll
    for (int mk = 1; mk < 64; mk <<= 1) acc += __shfl_xor(acc, mk, 64);
    if (lane == 0) wacc[q] = acc;
    __syncthreads();
    if (tid == 0) partial[blockIdx.x] = wacc[0] + wacc[1] + wacc[2] + wacc[3];
}

// Output: single float32 scalar.
__global__ __launch_bounds__(256) void nhll_finalize(
    const float* __restrict__ partial, float* __restrict__ out)
{
    __shared__ float red[4];
    float s = 0.f;
    for (int i = threadIdx.x; i < NB; i += 256) s += partial[i];
    for (int mk = 1; mk < 64; mk <<= 1) s += __shfl_xor(s, mk, 64);
    if ((threadIdx.x & 63) == 0) red[threadIdx.x >> 6] = s;
    __syncthreads();
    if (threadIdx.x == 0)
        out[0] = red[0] + red[1] + red[2] + red[3];
}

extern "C" void kernel_launch(void* const* d_in, const int* in_sizes, int n_in,
                              void* d_out, int out_size, void* d_ws, size_t ws_size,
                              hipStream_t stream) {
    const int*   events = (const int*)  d_in[0];   // event_seqs  [B,L] int32
    const int*   lens   = (const int*)  d_in[1];   // seqs_length [B]   int32
    const float* ttime  = (const float*)d_in[2];   // total_time  [B]
    const float* hidden = (const float*)d_in[3];   // [L,B,H]
    const float* cell   = (const float*)d_in[4];   // [L,B,H]
    const float* ctarg  = (const float*)d_in[5];   // [L,B,H]
    const float* outp   = (const float*)d_in[6];   // [L,B,H]
    const float* decay  = (const float*)d_in[7];   // [L,B,H]
    const float* simt   = (const float*)d_in[8];   // [L,B]
    const float* W      = (const float*)d_in[9];   // [H,K]
    const float* bias   = (const float*)d_in[10];  // [K]

    float* part = (float*)d_ws;                    // NB floats
    float* out  = (float*)d_out;

    nhll_main<<<NB, 256, 0, stream>>>(events, lens, ttime, hidden, cell, ctarg,
                                      outp, decay, simt, W, bias, part);
    nhll_finalize<<<1, 256, 0, stream>>>(part, out);
}